// Round 7
// baseline (432.112 us; speedup 1.0000x reference)
//
#include <hip/hip_runtime.h>

#define LNEPS 1e-5f

typedef __attribute__((ext_vector_type(8)))  short          bf16x8;
typedef __attribute__((ext_vector_type(8)))  unsigned short u16x8;
typedef __attribute__((ext_vector_type(4)))  float          f32x4;
typedef __attribute__((ext_vector_type(16))) float          f32x16;
typedef __attribute__((ext_vector_type(4)))  unsigned int   u32x4;

#define MFMA32(a, b, c) __builtin_amdgcn_mfma_f32_32x32x16_bf16((a), (b), (c), 0, 0, 0)

// workspace byte offsets (~26.9 MB)
#define WS_W2G  0          // 64 * 128KB  : W2*g1 ^T blob [s][i][t][lane] bf16x8
#define WS_A1   8388608    // 64*8*64*16B : layer-1 A-frags (W1o^T | c1)
#define WS_WPG  8912896    // 64*17*64*16B: layer-3 A-frags (Wp*g2 ^T | up,cp)
#define WS_UC2  10027008   // 64*256*4B   : packed bf16 (u[n], c2[n])
#define WS_MIDX 10092544   // 512*4B      : masked neighbor idx (-1 = masked)
#define WS_XG   10094592   // 64*16384*16B: prefab layer-1 B-words (masked bf16 x8)

union U8 { bf16x8 v; unsigned u[4]; };

__device__ __forceinline__ unsigned short f2bf(float v) {
  union { float f; unsigned u; } a; a.f = v;
  unsigned r = a.u + 0x7fffu + ((a.u >> 16) & 1u);   // RTNE
  return (unsigned short)(r >> 16);
}
__device__ __forceinline__ unsigned cvtpk(float lo, float hi) {
  unsigned r;
  asm("v_cvt_pk_bf16_f32 %0, %1, %2" : "=v"(r) : "v"(lo), "v"(hi));
  return r;
}
// swaps: a -> [a_lo | b_lo], b -> [a_hi | b_hi]
__device__ __forceinline__ void swap2(unsigned& a, unsigned& b) {
  asm volatile("v_permlane32_swap_b32 %0, %1" : "+v"(a), "+v"(b));
}

// ---- P1: mask format detect + masked index table (verified) ---------------
__global__ void prep_midx_k(const int* __restrict__ oidx,
                            const unsigned* __restrict__ mask32,
                            int* __restrict__ midx) {
  __shared__ int fgt1, ffl;
  const int t = threadIdx.x;            // 512 threads
  if (t == 0) { fgt1 = 0; ffl = 0; }
  __syncthreads();
  if (t < 128) {
    unsigned wv = mask32[t];
    if (wv == 0x3f800000u) atomicOr(&ffl, 1);
    else if (wv > 1u)      atomicOr(&fgt1, 1);
  }
  __syncthreads();
  const int mode = ffl ? 2 : (fgt1 ? 1 : 0);
  int mv;
  if (mode == 2)      mv = (((const float*)mask32)[t] != 0.0f) ? 1 : 0;
  else if (mode == 1) mv = (int)((const unsigned char*)mask32)[t];
  else                mv = ((const int*)mask32)[t];
  midx[t] = (mv != 0) ? oidx[t] : -1;
}

// ---- P1b: prefab layer-1 B-words: xg[s][row] = masked bf16 x[row][idx 0..7]
__global__ __launch_bounds__(256) void prep_xg_k(
    const float* __restrict__ x, const int* __restrict__ midx,
    u32x4* __restrict__ xg) {
  const int g = blockIdx.x * 256 + threadIdx.x;   // 1,048,576
  const int s = g >> 14, row = g & 16383;
  const float* xr = x + (size_t)row * 64;
  const int* mi = midx + s * 8;
  u32x4 w;
#pragma unroll
  for (int p = 0; p < 4; ++p) {
    const int m0 = mi[2 * p], m1 = mi[2 * p + 1];
    const float a = m0 < 0 ? 0.f : xr[m0];
    const float b = m1 < 0 ? 0.f : xr[m1];
    w[p] = (unsigned)f2bf(a) | ((unsigned)f2bf(b) << 16);
  }
  xg[g] = w;
}

// ---- P2: W2*g1 -> bf16 A-frag blob [s][i][t][lane] (verified) -------------
__global__ __launch_bounds__(256) void prep_w2g_k(
    const float* __restrict__ W2, const float* __restrict__ g1,
    unsigned short* __restrict__ w2g) {
  const int tid = blockIdx.x * 256 + threadIdx.x;   // 524288
  const int l = tid & 63;
  const int t = (tid >> 6) & 15;
  const int i = (tid >> 10) & 7;
  const int s = tid >> 13;
  const int n = i * 32 + (l & 31);
  const int h = l >> 5;
  const float* w = W2 + (size_t)s * 65536;          // [k][n]
  const float* g = g1 + s * 256;
  u16x8 v;
#pragma unroll
  for (int j = 0; j < 8; ++j) {
    const int k = t * 16 + h * 8 + j;
    v[j] = f2bf(w[k * 256 + n] * g[k]);
  }
  ((u16x8*)w2g)[tid] = v;
}

// ---- P3: u[n], c2[n] packed bf16 (verified) -------------------------------
__global__ __launch_bounds__(256) void prep_uc2_k(
    const float* __restrict__ W2, const float* __restrict__ g1,
    const float* __restrict__ be1, const float* __restrict__ b2,
    unsigned* __restrict__ uc2) {
  const int tid = blockIdx.x * 256 + threadIdx.x;   // 16384
  const int s = tid >> 8, n = tid & 255;
  const float* w = W2 + (size_t)s * 65536 + n;
  const float* g = g1 + s * 256;
  const float* be = be1 + s * 256;
  float u = 0.f, c = 0.f;
#pragma unroll 8
  for (int k = 0; k < 256; ++k) {
    const float wk = w[k * 256];
    u = fmaf(wk, g[k], u);
    c = fmaf(wk, be[k], c);
  }
  c += b2[tid];
  uc2[tid] = (unsigned)f2bf(u) | ((unsigned)f2bf(c) << 16);
}

// ---- P4: layer-1 A-frags (verified) ---------------------------------------
__global__ __launch_bounds__(256) void prep_a1_k(
    const float* __restrict__ W1, const float* __restrict__ b1,
    unsigned short* __restrict__ a1b) {
  const int tid = blockIdx.x * 256 + threadIdx.x;   // 32768
  const int l = tid & 63;
  const int i = (tid >> 6) & 7;
  const int s = tid >> 9;
  const int n = i * 32 + (l & 31);
  const float* w = W1 + (size_t)s * 72 * 256;
  u16x8 v;
#pragma unroll
  for (int j = 0; j < 8; ++j) v[j] = 0;
  if (l < 32) {
#pragma unroll
    for (int j = 0; j < 8; ++j) v[j] = f2bf(w[(64 + j) * 256 + n]);
  } else {
    v[0] = f2bf(w[s * 256 + n] + b1[s * 256 + n]);  // c1, rides k=8 (ones slot)
  }
  ((u16x8*)a1b)[tid] = v;
}

// ---- P5: layer-3 A-frags (verified) ---------------------------------------
__global__ __launch_bounds__(256) void prep_wpg_k(
    const float* __restrict__ Wp, const float* __restrict__ g2,
    const float* __restrict__ be2, const float* __restrict__ bp,
    unsigned short* __restrict__ wpg) {
  const int tid = blockIdx.x * 256 + threadIdx.x;   // 69632
  const int l = tid & 63;
  const int r = tid >> 6;
  const int t = r % 17;
  const int s = r / 17;
  const int a = l & 31;
  const int h = l >> 5;
  u16x8 v;
#pragma unroll
  for (int j = 0; j < 8; ++j) v[j] = 0;
  if (t < 16) {
    if (a < 16) {
      const float* w = Wp + (size_t)s * 4096;       // [k][a]
      const float* g = g2 + s * 256;
#pragma unroll
      for (int j = 0; j < 8; ++j) {
        const int k = t * 16 + h * 8 + j;
        v[j] = f2bf(w[k * 16 + a] * g[k]);
      }
    }
  } else if (h == 0 && a < 16) {
    const float* w = Wp + (size_t)s * 4096;
    float up = 0.f, cp = 0.f;
#pragma unroll 8
    for (int k = 0; k < 256; ++k) {
      const float wk = w[k * 16 + a];
      up = fmaf(wk, g2[s * 256 + k], up);
      cp = fmaf(wk, be2[s * 256 + k], cp);
    }
    cp += bp[s * 16 + a];
    v[0] = f2bf(up); v[1] = f2bf(cp);
  }
  ((u16x8*)wpg)[tid] = v;
}

// ---- pack one 32-n f32x16 tile -> two B-frags (pair-swap, verified) -------
__device__ __forceinline__ void pack_tile(const f32x16& a,
                                          unsigned* f0, unsigned* f1) {
  unsigned w0 = cvtpk(a[0], a[1]),   w1 = cvtpk(a[2], a[3]);
  unsigned w2 = cvtpk(a[4], a[5]),   w3 = cvtpk(a[6], a[7]);
  unsigned w4 = cvtpk(a[8], a[9]),   w5 = cvtpk(a[10], a[11]);
  unsigned w6 = cvtpk(a[12], a[13]), w7 = cvtpk(a[14], a[15]);
  swap2(w0, w2); swap2(w1, w3); swap2(w4, w6); swap2(w5, w7);
  f0[0] = w0; f0[1] = w1; f0[2] = w2; f0[3] = w3;
  f1[0] = w4; f1[1] = w5; f1[2] = w6; f1[3] = w7;
}

// ---- main fused kernel: 6-LDS/2-L2 operand split + prefab B1 --------------
__global__ __launch_bounds__(512, 2) void actor_main(
    const u32x4* __restrict__ xg,
    const unsigned short* __restrict__ w2g, const unsigned* __restrict__ uc2,
    const unsigned short* __restrict__ a1b, const unsigned short* __restrict__ wpg,
    float* __restrict__ out) {
  extern __shared__ char lds[];                 // 96KB: W2g n-tiles 0..5
  const int tid = threadIdx.x;
  const int wv = tid >> 6;
  const int l = tid & 63;
  const int bl = l & 31;
  const int h = l >> 5;
  const int s = blockIdx.x >> 2;
  const int rowstart = (blockIdx.x & 3) << 12;

  { // stage W2g n-tiles 0..5 (96KB), linear, conflict-free
    const u32x4* src = (const u32x4*)(w2g + (size_t)s * 65536);
    u32x4* dst = (u32x4*)lds;
#pragma unroll
    for (int i = 0; i < 12; ++i) dst[i * 512 + tid] = src[i * 512 + tid];
  }

  unsigned aext[8];
#pragma unroll
  for (int i = 0; i < 8; ++i) {
    const unsigned t = uc2[(s * 8 + i) * 32 + bl];
    aext[i] = h ? 0u : t;
  }
  const bf16x8* A1 = ((const bf16x8*)a1b) + (size_t)(s * 8) * 64 + l;
  const bf16x8* A3 = ((const bf16x8*)wpg) + (size_t)(s * 17) * 64 + l;
  const bf16x8* A2G = ((const bf16x8*)w2g) + (size_t)s * 8192 + l;  // tiles 6,7
  const char* ldsl = lds + (l << 4);
  const u32x4* XG = xg + ((size_t)s << 14);

  const int rbase = rowstart + wv * 32 + bl;

  // prologue: prefab B1 words for iter 0 (one coalesced 16B load)
  u32x4 gcur = XG[rbase];

  __syncthreads();   // only barrier: W2g staged

  for (int it = 0; it < 16; ++it) {
    const int row = rbase + it * 256;

    // ---- layer-1 B-frag directly from prefab words ----------------------
    U8 B1;
    B1.u[0] = h ? 0x00003F80u : gcur[0];   // h=1: k=8 -> 1.0 (c1 slot)
    B1.u[1] = h ? 0u : gcur[1];
    B1.u[2] = h ? 0u : gcur[2];
    B1.u[3] = h ? 0u : gcur[3];

    // prefetch next iteration's prefab (full iter of latency cover)
    gcur = XG[rbase + ((it + 1) & 15) * 256];

    // ---- phase A: fused L1 -> leaky/stats/pack -> L2, interleaved ------
    float s0 = 0.f, s1 = 0.f, q0 = 0.f, q1 = 0.f;
    f32x16 acc2[8];
    bf16x8 a1n = A1[64];             // A1 frag for tile 1
    bf16x8 Afc[6];
#pragma unroll
    for (int j = 0; j < 6; ++j)      // ds prefetch for t=0 (LDS tiles)
      Afc[j] = *(const bf16x8*)(ldsl + ((j * 16 + 0) << 10));
    bf16x8 Gc0 = A2G[(6 * 16 + 0) * 64];   // L2 frags t=0 (tiles 6,7)
    bf16x8 Gc1 = A2G[(7 * 16 + 0) * 64];

    f32x16 accP;
    { f32x16 z = {}; accP = MFMA32(A1[0], B1.v, z); }   // tile 0 L1

#pragma unroll
    for (int i = 0; i < 8; ++i) {
      // leaky + stats + pack of tile i (VALU; overlaps in-flight ds/MAI)
      f32x16 yv;
#pragma unroll
      for (int r = 0; r < 16; ++r) {
        float v = accP[r];
        v = fmaxf(v, 0.01f * v);
        yv[r] = v;
        if (r & 1) { s1 += v; q1 = fmaf(v, v, q1); }
        else       { s0 += v; q0 = fmaf(v, v, q0); }
      }
      U8 Bf0, Bf1;
      pack_tile(yv, Bf0.u, Bf1.u);

      // issue next tile's L1 MFMA now (accP dead; ~17 MFMAs before use)
      if (i < 7) {
        f32x16 z = {};
        accP = MFMA32(a1n, B1.v, z);
        if (i < 6) a1n = A1[(i + 2) * 64];
      }

      // k-step t=2i: 6 LDS frags + 2 L2 frags
#pragma unroll
      for (int j = 0; j < 6; ++j) {
        if (i == 0) { f32x16 zz = {}; acc2[j] = MFMA32(Afc[j], Bf0.v, zz); }
        else        { acc2[j] = MFMA32(Afc[j], Bf0.v, acc2[j]); }
      }
      if (i == 0) { f32x16 zz = {}; acc2[6] = MFMA32(Gc0, Bf0.v, zz); }
      else        { acc2[6] = MFMA32(Gc0, Bf0.v, acc2[6]); }
      if (i == 0) { f32x16 zz = {}; acc2[7] = MFMA32(Gc1, Bf0.v, zz); }
      else        { acc2[7] = MFMA32(Gc1, Bf0.v, acc2[7]); }

      // load + k-step t=2i+1
      bf16x8 Afn[6];
#pragma unroll
      for (int j = 0; j < 6; ++j)
        Afn[j] = *(const bf16x8*)(ldsl + ((j * 16 + 2 * i + 1) << 10));
      bf16x8 Gn0 = A2G[(6 * 16 + 2 * i + 1) * 64];
      bf16x8 Gn1 = A2G[(7 * 16 + 2 * i + 1) * 64];
#pragma unroll
      for (int j = 0; j < 6; ++j) acc2[j] = MFMA32(Afn[j], Bf1.v, acc2[j]);
      acc2[6] = MFMA32(Gn0, Bf1.v, acc2[6]);
      acc2[7] = MFMA32(Gn1, Bf1.v, acc2[7]);

      // prefetch t=2i+2 for next step
      if (i < 7) {
#pragma unroll
        for (int j = 0; j < 6; ++j)
          Afc[j] = *(const bf16x8*)(ldsl + ((j * 16 + 2 * i + 2) << 10));
        Gc0 = A2G[(6 * 16 + 2 * i + 2) * 64];
        Gc1 = A2G[(7 * 16 + 2 * i + 2) * 64];
      }
    }

    // ---- LN1 stats finalize + rank-1 correction k-step ------------------
    float sum = s0 + s1, ssq = q0 + q1;
    sum += __shfl_xor(sum, 32, 64);
    ssq += __shfl_xor(ssq, 32, 64);
    const float m1 = sum * 0.00390625f;
    const float var1 = fmaf(ssq, 0.00390625f, -m1 * m1) + LNEPS;
    const float rho1 = rsqrtf(var1);
    const float std1 = var1 * rho1;               // = 1/rho1
    const unsigned be2w = cvtpk(-m1, std1);
    // prefetch first layer-3 A-frags (VMEM, hidden under corr MFMAs)
    bf16x8 p0 = A3[0], p1 = A3[64];
    {
      U8 Bx; Bx.u[0] = h ? 0u : be2w; Bx.u[1] = 0; Bx.u[2] = 0; Bx.u[3] = 0;
#pragma unroll
      for (int i = 0; i < 8; ++i) {
        U8 Ax; Ax.u[0] = aext[i]; Ax.u[1] = 0; Ax.u[2] = 0; Ax.u[3] = 0;
        acc2[i] = MFMA32(Ax.v, Bx.v, acc2[i]);
      }
    }

    // ---- phase B: fused leaky/stats2/pack + layer-3 (A3 prefetch) -------
    f32x16 a3a = {}, a3b = {};
    s0 = s1 = q0 = q1 = 0.f;
#pragma unroll
    for (int i = 0; i < 8; ++i) {
      bf16x8 n0, n1;
      if (i < 7) { n0 = A3[(2 * i + 2) * 64]; n1 = A3[(2 * i + 3) * 64]; }
      else       { n0 = A3[16 * 64]; n1 = p1; }
      f32x16 yv;
#pragma unroll
      for (int r = 0; r < 16; ++r) {
        float v = acc2[i][r];
        v = fmaxf(v, 0.01f * v);
        yv[r] = v;
        if (r & 1) { s1 += v; q1 = fmaf(v, v, q1); }
        else       { s0 += v; q0 = fmaf(v, v, q0); }
      }
      U8 Bf0, Bf1;
      pack_tile(yv, Bf0.u, Bf1.u);
      a3a = MFMA32(p0, Bf0.v, a3a);
      a3b = MFMA32(p1, Bf1.v, a3b);
      p0 = n0; p1 = n1;
    }
    float sum2 = s0 + s1, ssq2 = q0 + q1;
    sum2 += __shfl_xor(sum2, 32, 64);
    ssq2 += __shfl_xor(ssq2, 32, 64);
    const float mp = sum2 * 0.00390625f;
    const float qp = ssq2 * 0.00390625f;
    const float var2 = rho1 * rho1 * fmaf(-mp, mp, qp) + LNEPS;
    const float rho2 = rsqrtf(var2);
    const float sigma = rho1 * rho2;
    const float inv = var2 * rho2 * std1;         // = 1/sigma
    const unsigned be3w = cvtpk(-mp, inv);
    { // LN2 rank-1 correction k-step (p0 holds A3[16*64])
      U8 Bx; Bx.u[0] = h ? 0u : be3w; Bx.u[1] = 0; Bx.u[2] = 0; Bx.u[3] = 0;
      a3a = MFMA32(p0, Bx.v, a3a);
    }

    // ---- log-softmax + store --------------------------------------------
    float lg[8];
#pragma unroll
    for (int r = 0; r < 8; ++r) lg[r] = sigma * (a3a[r] + a3b[r]);
    float mx = fmaxf(fmaxf(fmaxf(lg[0], lg[1]), fmaxf(lg[2], lg[3])),
                     fmaxf(fmaxf(lg[4], lg[5]), fmaxf(lg[6], lg[7])));
    mx = fmaxf(mx, __shfl_xor(mx, 32, 64));
    float es = 0.f;
#pragma unroll
    for (int r = 0; r < 8; ++r) es += __expf(lg[r] - mx);
    es += __shfl_xor(es, 32, 64);
    const float lse = mx + __logf(es);

    const size_t ob = (((size_t)row << 6) + s) * 16 + (h << 2);
    f32x4 v0 = {lg[0], lg[1], lg[2], lg[3]};
    f32x4 v1 = {lg[4], lg[5], lg[6], lg[7]};
    *(f32x4*)(out + ob) = v0;
    *(f32x4*)(out + ob + 8) = v1;
    f32x4 w0 = {lg[0] - lse, lg[1] - lse, lg[2] - lse, lg[3] - lse};
    f32x4 w1 = {lg[4] - lse, lg[5] - lse, lg[6] - lse, lg[7] - lse};
    *(f32x4*)(out + 16777216 + ob) = w0;
    *(f32x4*)(out + 16777216 + ob + 8) = w1;
  }
}

extern "C" void kernel_launch(void* const* d_in, const int* in_sizes, int n_in,
                              void* d_out, int out_size, void* d_ws, size_t ws_size,
                              hipStream_t stream) {
  const float* x    = (const float*)d_in[0];
  const int*   oidx = (const int*)d_in[1];
  const unsigned* omask = (const unsigned*)d_in[2];
  const float* W1 = (const float*)d_in[3];
  const float* b1 = (const float*)d_in[4];
  const float* g1 = (const float*)d_in[5];
  const float* be1 = (const float*)d_in[6];
  const float* W2 = (const float*)d_in[7];
  const float* b2 = (const float*)d_in[8];
  const float* g2 = (const float*)d_in[9];
  const float* be2 = (const float*)d_in[10];
  const float* Wp = (const float*)d_in[11];
  const float* bp = (const float*)d_in[12];
  float* out = (float*)d_out;

  char* ws = (char*)d_ws;
  unsigned short* wsW2G = (unsigned short*)(ws + WS_W2G);
  unsigned short* wsA1  = (unsigned short*)(ws + WS_A1);
  unsigned short* wsWPG = (unsigned short*)(ws + WS_WPG);
  unsigned*       wsUC2 = (unsigned*)(ws + WS_UC2);
  int*            wsMIDX = (int*)(ws + WS_MIDX);
  u32x4*          wsXG   = (u32x4*)(ws + WS_XG);

  prep_midx_k<<<1, 512, 0, stream>>>(oidx, omask, wsMIDX);
  prep_xg_k<<<4096, 256, 0, stream>>>(x, wsMIDX, wsXG);
  prep_w2g_k<<<2048, 256, 0, stream>>>(W2, g1, wsW2G);
  prep_uc2_k<<<64, 256, 0, stream>>>(W2, g1, be1, b2, wsUC2);
  prep_a1_k<<<128, 256, 0, stream>>>(W1, b1, wsA1);
  prep_wpg_k<<<272, 256, 0, stream>>>(Wp, g2, be2, bp, wsWPG);

  hipFuncSetAttribute((const void*)actor_main,
                      hipFuncAttributeMaxDynamicSharedMemorySize, 98304);
  actor_main<<<256, 512, 98304, stream>>>(
      wsXG, wsW2G, wsUC2, wsA1, wsWPG, out);
}

// Round 8
// 314.960 us; speedup vs baseline: 1.3720x; 1.3720x over previous
//
#include <hip/hip_runtime.h>

#define LNEPS 1e-5f

typedef __attribute__((ext_vector_type(8)))  short          bf16x8;
typedef __attribute__((ext_vector_type(8)))  unsigned short u16x8;
typedef __attribute__((ext_vector_type(4)))  float          f32x4;
typedef __attribute__((ext_vector_type(16))) float          f32x16;
typedef __attribute__((ext_vector_type(4)))  unsigned int   u32x4;

#define MFMA32(a, b, c) __builtin_amdgcn_mfma_f32_32x32x16_bf16((a), (b), (c), 0, 0, 0)

// workspace byte offsets (~26.9 MB)
#define WS_W2G  0          // 64 * 128KB  : W2*g1 ^T blob [s][i][t][lane] bf16x8
#define WS_A1   8388608    // 64*8*64*16B : layer-1 A-frags (W1o^T | c1)
#define WS_WPG  8912896    // 64*17*64*16B: layer-3 A-frags (Wp*g2 ^T | up,cp)
#define WS_UC2  10027008   // 64*256*4B   : packed bf16 (u[n], c2[n])
#define WS_MIDX 10092544   // 512*4B      : masked neighbor idx (-1 = masked)
#define WS_XG   10094592   // 64*16384*16B: prefab layer-1 B-words (masked bf16 x8)

union U8 { bf16x8 v; unsigned u[4]; };

__device__ __forceinline__ unsigned short f2bf(float v) {
  union { float f; unsigned u; } a; a.f = v;
  unsigned r = a.u + 0x7fffu + ((a.u >> 16) & 1u);   // RTNE
  return (unsigned short)(r >> 16);
}
__device__ __forceinline__ unsigned cvtpk(float lo, float hi) {
  unsigned r;
  asm("v_cvt_pk_bf16_f32 %0, %1, %2" : "=v"(r) : "v"(lo), "v"(hi));
  return r;
}
// swaps: a -> [a_lo | b_lo], b -> [a_hi | b_hi]
__device__ __forceinline__ void swap2(unsigned& a, unsigned& b) {
  asm volatile("v_permlane32_swap_b32 %0, %1" : "+v"(a), "+v"(b));
}

// ---- P1: mask format detect + masked index table (verified) ---------------
__global__ void prep_midx_k(const int* __restrict__ oidx,
                            const unsigned* __restrict__ mask32,
                            int* __restrict__ midx) {
  __shared__ int fgt1, ffl;
  const int t = threadIdx.x;            // 512 threads
  if (t == 0) { fgt1 = 0; ffl = 0; }
  __syncthreads();
  if (t < 128) {
    unsigned wv = mask32[t];
    if (wv == 0x3f800000u) atomicOr(&ffl, 1);
    else if (wv > 1u)      atomicOr(&fgt1, 1);
  }
  __syncthreads();
  const int mode = ffl ? 2 : (fgt1 ? 1 : 0);
  int mv;
  if (mode == 2)      mv = (((const float*)mask32)[t] != 0.0f) ? 1 : 0;
  else if (mode == 1) mv = (int)((const unsigned char*)mask32)[t];
  else                mv = ((const int*)mask32)[t];
  midx[t] = (mv != 0) ? oidx[t] : -1;
}

// ---- P1b: prefab layer-1 B-words: xg[s][row] = masked bf16 x[row][idx 0..7]
__global__ __launch_bounds__(256) void prep_xg_k(
    const float* __restrict__ x, const int* __restrict__ midx,
    u32x4* __restrict__ xg) {
  const int g = blockIdx.x * 256 + threadIdx.x;   // 1,048,576
  const int s = g >> 14, row = g & 16383;
  const float* xr = x + (size_t)row * 64;
  const int* mi = midx + s * 8;
  u32x4 w;
#pragma unroll
  for (int p = 0; p < 4; ++p) {
    const int m0 = mi[2 * p], m1 = mi[2 * p + 1];
    const float a = m0 < 0 ? 0.f : xr[m0];
    const float b = m1 < 0 ? 0.f : xr[m1];
    w[p] = (unsigned)f2bf(a) | ((unsigned)f2bf(b) << 16);
  }
  xg[g] = w;
}

// ---- P2: W2*g1 -> bf16 A-frag blob [s][i][t][lane] (verified) -------------
__global__ __launch_bounds__(256) void prep_w2g_k(
    const float* __restrict__ W2, const float* __restrict__ g1,
    unsigned short* __restrict__ w2g) {
  const int tid = blockIdx.x * 256 + threadIdx.x;   // 524288
  const int l = tid & 63;
  const int t = (tid >> 6) & 15;
  const int i = (tid >> 10) & 7;
  const int s = tid >> 13;
  const int n = i * 32 + (l & 31);
  const int h = l >> 5;
  const float* w = W2 + (size_t)s * 65536;          // [k][n]
  const float* g = g1 + s * 256;
  u16x8 v;
#pragma unroll
  for (int j = 0; j < 8; ++j) {
    const int k = t * 16 + h * 8 + j;
    v[j] = f2bf(w[k * 256 + n] * g[k]);
  }
  ((u16x8*)w2g)[tid] = v;
}

// ---- P3: u[n], c2[n] packed bf16 (verified) -------------------------------
__global__ __launch_bounds__(256) void prep_uc2_k(
    const float* __restrict__ W2, const float* __restrict__ g1,
    const float* __restrict__ be1, const float* __restrict__ b2,
    unsigned* __restrict__ uc2) {
  const int tid = blockIdx.x * 256 + threadIdx.x;   // 16384
  const int s = tid >> 8, n = tid & 255;
  const float* w = W2 + (size_t)s * 65536 + n;
  const float* g = g1 + s * 256;
  const float* be = be1 + s * 256;
  float u = 0.f, c = 0.f;
#pragma unroll 8
  for (int k = 0; k < 256; ++k) {
    const float wk = w[k * 256];
    u = fmaf(wk, g[k], u);
    c = fmaf(wk, be[k], c);
  }
  c += b2[tid];
  uc2[tid] = (unsigned)f2bf(u) | ((unsigned)f2bf(c) << 16);
}

// ---- P4: layer-1 A-frags (verified) ---------------------------------------
__global__ __launch_bounds__(256) void prep_a1_k(
    const float* __restrict__ W1, const float* __restrict__ b1,
    unsigned short* __restrict__ a1b) {
  const int tid = blockIdx.x * 256 + threadIdx.x;   // 32768
  const int l = tid & 63;
  const int i = (tid >> 6) & 7;
  const int s = tid >> 9;
  const int n = i * 32 + (l & 31);
  const float* w = W1 + (size_t)s * 72 * 256;
  u16x8 v;
#pragma unroll
  for (int j = 0; j < 8; ++j) v[j] = 0;
  if (l < 32) {
#pragma unroll
    for (int j = 0; j < 8; ++j) v[j] = f2bf(w[(64 + j) * 256 + n]);
  } else {
    v[0] = f2bf(w[s * 256 + n] + b1[s * 256 + n]);  // c1, rides k=8 (ones slot)
  }
  ((u16x8*)a1b)[tid] = v;
}

// ---- P5: layer-3 A-frags (verified) ---------------------------------------
__global__ __launch_bounds__(256) void prep_wpg_k(
    const float* __restrict__ Wp, const float* __restrict__ g2,
    const float* __restrict__ be2, const float* __restrict__ bp,
    unsigned short* __restrict__ wpg) {
  const int tid = blockIdx.x * 256 + threadIdx.x;   // 69632
  const int l = tid & 63;
  const int r = tid >> 6;
  const int t = r % 17;
  const int s = r / 17;
  const int a = l & 31;
  const int h = l >> 5;
  u16x8 v;
#pragma unroll
  for (int j = 0; j < 8; ++j) v[j] = 0;
  if (t < 16) {
    if (a < 16) {
      const float* w = Wp + (size_t)s * 4096;       // [k][a]
      const float* g = g2 + s * 256;
#pragma unroll
      for (int j = 0; j < 8; ++j) {
        const int k = t * 16 + h * 8 + j;
        v[j] = f2bf(w[k * 16 + a] * g[k]);
      }
    }
  } else if (h == 0 && a < 16) {
    const float* w = Wp + (size_t)s * 4096;
    float up = 0.f, cp = 0.f;
#pragma unroll 8
    for (int k = 0; k < 256; ++k) {
      const float wk = w[k * 16 + a];
      up = fmaf(wk, g2[s * 256 + k], up);
      cp = fmaf(wk, be2[s * 256 + k], cp);
    }
    cp += bp[s * 16 + a];
    v[0] = f2bf(up); v[1] = f2bf(cp);
  }
  ((u16x8*)wpg)[tid] = v;
}

// ---- pack one 32-n f32x16 tile -> two B-frags (pair-swap, verified) -------
__device__ __forceinline__ void pack_tile(const f32x16& a,
                                          unsigned* f0, unsigned* f1) {
  unsigned w0 = cvtpk(a[0], a[1]),   w1 = cvtpk(a[2], a[3]);
  unsigned w2 = cvtpk(a[4], a[5]),   w3 = cvtpk(a[6], a[7]);
  unsigned w4 = cvtpk(a[8], a[9]),   w5 = cvtpk(a[10], a[11]);
  unsigned w6 = cvtpk(a[12], a[13]), w7 = cvtpk(a[14], a[15]);
  swap2(w0, w2); swap2(w1, w3); swap2(w4, w6); swap2(w5, w7);
  f0[0] = w0; f0[1] = w1; f0[2] = w2; f0[3] = w3;
  f1[0] = w4; f1[1] = w5; f1[2] = w6; f1[3] = w7;
}

// ---- main fused kernel: n-tile-outer, double-buffered LDS pipeline --------
__global__ __launch_bounds__(512, 2) void actor_main(
    const u32x4* __restrict__ xg,
    const unsigned short* __restrict__ w2g, const unsigned* __restrict__ uc2,
    const unsigned short* __restrict__ a1b, const unsigned short* __restrict__ wpg,
    float* __restrict__ out) {
  extern __shared__ char lds[];                 // 128KB W2g blob
  const int tid = threadIdx.x;
  const int wv = tid >> 6;
  const int l = tid & 63;
  const int bl = l & 31;
  const int h = l >> 5;
  const int s = blockIdx.x & 63;                // XCD-aligned: 4 blocks/state on 1 XCD
  const int rowstart = (blockIdx.x >> 6) << 12;

  { // stage W2g blob (128KB), linear, conflict-free
    const u32x4* src = (const u32x4*)(w2g + (size_t)s * 65536);
    u32x4* dst = (u32x4*)lds;
#pragma unroll
    for (int i = 0; i < 16; ++i) dst[i * 512 + tid] = src[i * 512 + tid];
  }

  unsigned aext[8];
#pragma unroll
  for (int i = 0; i < 8; ++i) {
    const unsigned t = uc2[(s * 8 + i) * 32 + bl];
    aext[i] = h ? 0u : t;
  }
  const bf16x8* A1 = ((const bf16x8*)a1b) + (size_t)(s * 8) * 64 + l;
  const bf16x8* A3 = ((const bf16x8*)wpg) + (size_t)(s * 17) * 64 + l;
  const char* ldsl = lds + (l << 4);
  const u32x4* XG = xg + ((size_t)s << 14);

  const int rbase = rowstart + wv * 32 + bl;

  // prologue: prefab B1 words for iter 0 (one coalesced 16B load)
  u32x4 gcur = XG[rbase];

  __syncthreads();   // only barrier: W2g staged

  for (int it = 0; it < 16; ++it) {
    const int row = rbase + it * 256;

    // ---- early: tile-0 half-0 LDS loads (consumed after L1 head) --------
    bf16x8 bufA[8];
#pragma unroll
    for (int t = 0; t < 8; ++t)
      bufA[t] = *(const bf16x8*)(ldsl + (t << 10));

    // ---- layer-1 B-frag directly from prefab words ----------------------
    U8 B1;
    B1.u[0] = h ? 0x00003F80u : gcur[0];   // h=1: k=8 -> 1.0 (c1 slot)
    B1.u[1] = h ? 0u : gcur[1];
    B1.u[2] = h ? 0u : gcur[2];
    B1.u[3] = h ? 0u : gcur[3];

    // prefetch next iteration's prefab (full iter of latency cover)
    gcur = XG[rbase + ((it + 1) & 15) * 256];

    // ---- L1 head: 8 tiles -> leaky/stats1/pack into yf ------------------
    float s0 = 0.f, s1 = 0.f, q0 = 0.f, q1 = 0.f;
    unsigned yf[16][4];
    bf16x8 a1n = A1[64];
    f32x16 accP;
    { f32x16 z = {}; accP = MFMA32(A1[0], B1.v, z); }
#pragma unroll
    for (int i = 0; i < 8; ++i) {
      f32x16 yv;
#pragma unroll
      for (int r = 0; r < 16; ++r) {
        float v = accP[r];
        v = fmaxf(v, 0.01f * v);
        yv[r] = v;
        if (r & 1) { s1 += v; q1 = fmaf(v, v, q1); }
        else       { s0 += v; q0 = fmaf(v, v, q0); }
      }
      if (i < 7) {
        f32x16 z = {};
        accP = MFMA32(a1n, B1.v, z);
        if (i < 6) a1n = A1[(i + 2) * 64];
      }
      pack_tile(yv, yf[2 * i], yf[2 * i + 1]);
    }
    float sum = s0 + s1, ssq = q0 + q1;
    sum += __shfl_xor(sum, 32, 64);
    ssq += __shfl_xor(ssq, 32, 64);
    const float m1 = sum * 0.00390625f;
    const float var1 = fmaf(ssq, 0.00390625f, -m1 * m1) + LNEPS;
    const float rho1 = rsqrtf(var1);
    const float std1 = var1 * rho1;               // = 1/rho1
    const unsigned be2w = cvtpk(-m1, std1);
    U8 Bx2; Bx2.u[0] = h ? 0u : be2w; Bx2.u[1] = 0; Bx2.u[2] = 0; Bx2.u[3] = 0;

    // ---- fused layer-2 + LN2 + layer-3 over n-tiles ---------------------
    f32x16 a3a = {}, a3b = {};
    s0 = s1 = q0 = q1 = 0.f;
    bf16x8 p0 = A3[0], p1 = A3[64];
#pragma unroll
    for (int j = 0; j < 8; ++j) {
      const char* tb = ldsl + (j << 14);
      // half-1 loads for this tile (cover: 8 MFMAs below)
      bf16x8 bufB[8];
#pragma unroll
      for (int t = 0; t < 8; ++t)
        bufB[t] = *(const bf16x8*)(tb + ((t + 8) << 10));
      // k-steps t=0..7 from bufA
      f32x16 acc;
#pragma unroll
      for (int t = 0; t < 8; ++t) {
        U8 Bf; Bf.u[0] = yf[t][0]; Bf.u[1] = yf[t][1];
        Bf.u[2] = yf[t][2]; Bf.u[3] = yf[t][3];
        if (t == 0) { f32x16 z = {}; acc = MFMA32(bufA[0], Bf.v, z); }
        else        { acc = MFMA32(bufA[t], Bf.v, acc); }
      }
      // next tile half-0 loads (cover: 8 MFMAs + corr + epilogue)
      if (j < 7) {
        const char* tn = ldsl + ((j + 1) << 14);
#pragma unroll
        for (int t = 0; t < 8; ++t)
          bufA[t] = *(const bf16x8*)(tn + (t << 10));
      }
      // k-steps t=8..15 from bufB
#pragma unroll
      for (int t = 0; t < 8; ++t) {
        U8 Bf; Bf.u[0] = yf[t + 8][0]; Bf.u[1] = yf[t + 8][1];
        Bf.u[2] = yf[t + 8][2]; Bf.u[3] = yf[t + 8][3];
        acc = MFMA32(bufB[t], Bf.v, acc);
      }
      { // LN1 rank-1 correction k-step
        U8 Ax; Ax.u[0] = aext[j]; Ax.u[1] = 0; Ax.u[2] = 0; Ax.u[3] = 0;
        acc = MFMA32(Ax.v, Bx2.v, acc);
      }
      // epilogue: leaky + stats2 + pack + 2 layer-3 MFMAs; acc dies here
      bf16x8 n0, n1;
      if (j < 7) { n0 = A3[(2 * j + 2) * 64]; n1 = A3[(2 * j + 3) * 64]; }
      else       { n0 = A3[16 * 64]; n1 = p1; }
      f32x16 yv;
#pragma unroll
      for (int r = 0; r < 16; ++r) {
        float v = acc[r];
        v = fmaxf(v, 0.01f * v);
        yv[r] = v;
        if (r & 1) { s1 += v; q1 = fmaf(v, v, q1); }
        else       { s0 += v; q0 = fmaf(v, v, q0); }
      }
      U8 Bf0, Bf1;
      pack_tile(yv, Bf0.u, Bf1.u);
      a3a = MFMA32(p0, Bf0.v, a3a);
      a3b = MFMA32(p1, Bf1.v, a3b);
      p0 = n0; p1 = n1;
    }
    float sum2 = s0 + s1, ssq2 = q0 + q1;
    sum2 += __shfl_xor(sum2, 32, 64);
    ssq2 += __shfl_xor(ssq2, 32, 64);
    const float mp = sum2 * 0.00390625f;
    const float qp = ssq2 * 0.00390625f;
    const float var2 = rho1 * rho1 * fmaf(-mp, mp, qp) + LNEPS;
    const float rho2 = rsqrtf(var2);
    const float sigma = rho1 * rho2;
    const float inv = var2 * rho2 * std1;         // = 1/sigma
    const unsigned be3w = cvtpk(-mp, inv);
    { // LN2 rank-1 correction k-step (p0 holds A3[16*64])
      U8 Bx; Bx.u[0] = h ? 0u : be3w; Bx.u[1] = 0; Bx.u[2] = 0; Bx.u[3] = 0;
      a3a = MFMA32(p0, Bx.v, a3a);
    }

    // ---- log-softmax + store --------------------------------------------
    float lg[8];
#pragma unroll
    for (int r = 0; r < 8; ++r) lg[r] = sigma * (a3a[r] + a3b[r]);
    float mx = fmaxf(fmaxf(fmaxf(lg[0], lg[1]), fmaxf(lg[2], lg[3])),
                     fmaxf(fmaxf(lg[4], lg[5]), fmaxf(lg[6], lg[7])));
    mx = fmaxf(mx, __shfl_xor(mx, 32, 64));
    float es = 0.f;
#pragma unroll
    for (int r = 0; r < 8; ++r) es += __expf(lg[r] - mx);
    es += __shfl_xor(es, 32, 64);
    const float lse = mx + __logf(es);

    const size_t ob = (((size_t)row << 6) + s) * 16 + (h << 2);
    f32x4 v0 = {lg[0], lg[1], lg[2], lg[3]};
    f32x4 v1 = {lg[4], lg[5], lg[6], lg[7]};
    *(f32x4*)(out + ob) = v0;
    *(f32x4*)(out + ob + 8) = v1;
    f32x4 w0 = {lg[0] - lse, lg[1] - lse, lg[2] - lse, lg[3] - lse};
    f32x4 w1 = {lg[4] - lse, lg[5] - lse, lg[6] - lse, lg[7] - lse};
    *(f32x4*)(out + 16777216 + ob) = w0;
    *(f32x4*)(out + 16777216 + ob + 8) = w1;
  }
}

extern "C" void kernel_launch(void* const* d_in, const int* in_sizes, int n_in,
                              void* d_out, int out_size, void* d_ws, size_t ws_size,
                              hipStream_t stream) {
  const float* x    = (const float*)d_in[0];
  const int*   oidx = (const int*)d_in[1];
  const unsigned* omask = (const unsigned*)d_in[2];
  const float* W1 = (const float*)d_in[3];
  const float* b1 = (const float*)d_in[4];
  const float* g1 = (const float*)d_in[5];
  const float* be1 = (const float*)d_in[6];
  const float* W2 = (const float*)d_in[7];
  const float* b2 = (const float*)d_in[8];
  const float* g2 = (const float*)d_in[9];
  const float* be2 = (const float*)d_in[10];
  const float* Wp = (const float*)d_in[11];
  const float* bp = (const float*)d_in[12];
  float* out = (float*)d_out;

  char* ws = (char*)d_ws;
  unsigned short* wsW2G = (unsigned short*)(ws + WS_W2G);
  unsigned short* wsA1  = (unsigned short*)(ws + WS_A1);
  unsigned short* wsWPG = (unsigned short*)(ws + WS_WPG);
  unsigned*       wsUC2 = (unsigned*)(ws + WS_UC2);
  int*            wsMIDX = (int*)(ws + WS_MIDX);
  u32x4*          wsXG   = (u32x4*)(ws + WS_XG);

  prep_midx_k<<<1, 512, 0, stream>>>(oidx, omask, wsMIDX);
  prep_xg_k<<<4096, 256, 0, stream>>>(x, wsMIDX, wsXG);
  prep_w2g_k<<<2048, 256, 0, stream>>>(W2, g1, wsW2G);
  prep_uc2_k<<<64, 256, 0, stream>>>(W2, g1, be1, b2, wsUC2);
  prep_a1_k<<<128, 256, 0, stream>>>(W1, b1, wsA1);
  prep_wpg_k<<<272, 256, 0, stream>>>(Wp, g2, be2, bp, wsWPG);

  hipFuncSetAttribute((const void*)actor_main,
                      hipFuncAttributeMaxDynamicSharedMemorySize, 131072);
  actor_main<<<256, 512, 131072, stream>>>(
      wsXG, wsW2G, wsUC2, wsA1, wsWPG, out);
}

// Round 9
// 313.016 us; speedup vs baseline: 1.3805x; 1.0062x over previous
//
#include <hip/hip_runtime.h>

#define LNEPS 1e-5f

typedef __attribute__((ext_vector_type(8)))  short          bf16x8;
typedef __attribute__((ext_vector_type(8)))  unsigned short u16x8;
typedef __attribute__((ext_vector_type(2)))  float          f32x2;
typedef __attribute__((ext_vector_type(4)))  float          f32x4;
typedef __attribute__((ext_vector_type(16))) float          f32x16;
typedef __attribute__((ext_vector_type(4)))  unsigned int   u32x4;

#define MFMA32(a, b, c) __builtin_amdgcn_mfma_f32_32x32x16_bf16((a), (b), (c), 0, 0, 0)

// workspace byte offsets (~26.9 MB)
#define WS_W2G  0          // 64 * 128KB  : W2*g1 ^T blob [s][i][t][lane] bf16x8
#define WS_A1   8388608    // 64*8*64*16B : layer-1 A-frags (W1o^T | c1)
#define WS_WPG  8912896    // 64*17*64*16B: layer-3 A-frags (Wp*g2 ^T | up,cp)
#define WS_UC2  10027008   // 64*256*4B   : packed bf16 (u[n], c2[n])
#define WS_MIDX 10092544   // 512*4B      : masked neighbor idx (-1 = masked)
#define WS_XG   10094592   // 64*16384*16B: prefab layer-1 B-words (masked bf16 x8)

union U8 { bf16x8 v; unsigned u[4]; };

__device__ __forceinline__ unsigned short f2bf(float v) {
  union { float f; unsigned u; } a; a.f = v;
  unsigned r = a.u + 0x7fffu + ((a.u >> 16) & 1u);   // RTNE
  return (unsigned short)(r >> 16);
}
__device__ __forceinline__ unsigned cvtpk(float lo, float hi) {
  unsigned r;
  asm("v_cvt_pk_bf16_f32 %0, %1, %2" : "=v"(r) : "v"(lo), "v"(hi));
  return r;
}
// swaps: a -> [a_lo | b_lo], b -> [a_hi | b_hi]
__device__ __forceinline__ void swap2(unsigned& a, unsigned& b) {
  asm volatile("v_permlane32_swap_b32 %0, %1" : "+v"(a), "+v"(b));
}
// packed dual-f32 ops (VOP3P, CDNA2+)
__device__ __forceinline__ f32x2 pk_mul(f32x2 a, f32x2 b) {
  f32x2 d; asm("v_pk_mul_f32 %0, %1, %2" : "=v"(d) : "v"(a), "v"(b)); return d;
}
__device__ __forceinline__ f32x2 pk_add(f32x2 a, f32x2 b) {
  f32x2 d; asm("v_pk_add_f32 %0, %1, %2" : "=v"(d) : "v"(a), "v"(b)); return d;
}
__device__ __forceinline__ f32x2 pk_fma(f32x2 a, f32x2 b, f32x2 c) {
  f32x2 d; asm("v_pk_fma_f32 %0, %1, %2, %3" : "=v"(d) : "v"(a), "v"(b), "v"(c)); return d;
}

// ---- P1: mask format detect + masked index table (verified) ---------------
__global__ void prep_midx_k(const int* __restrict__ oidx,
                            const unsigned* __restrict__ mask32,
                            int* __restrict__ midx) {
  __shared__ int fgt1, ffl;
  const int t = threadIdx.x;            // 512 threads
  if (t == 0) { fgt1 = 0; ffl = 0; }
  __syncthreads();
  if (t < 128) {
    unsigned wv = mask32[t];
    if (wv == 0x3f800000u) atomicOr(&ffl, 1);
    else if (wv > 1u)      atomicOr(&fgt1, 1);
  }
  __syncthreads();
  const int mode = ffl ? 2 : (fgt1 ? 1 : 0);
  int mv;
  if (mode == 2)      mv = (((const float*)mask32)[t] != 0.0f) ? 1 : 0;
  else if (mode == 1) mv = (int)((const unsigned char*)mask32)[t];
  else                mv = ((const int*)mask32)[t];
  midx[t] = (mv != 0) ? oidx[t] : -1;
}

// ---- P1b: prefab layer-1 B-words: xg[s][row] = masked bf16 x[row][idx 0..7]
__global__ __launch_bounds__(256) void prep_xg_k(
    const float* __restrict__ x, const int* __restrict__ midx,
    u32x4* __restrict__ xg) {
  const int g = blockIdx.x * 256 + threadIdx.x;   // 1,048,576
  const int s = g >> 14, row = g & 16383;
  const float* xr = x + (size_t)row * 64;
  const int* mi = midx + s * 8;
  u32x4 w;
#pragma unroll
  for (int p = 0; p < 4; ++p) {
    const int m0 = mi[2 * p], m1 = mi[2 * p + 1];
    const float a = m0 < 0 ? 0.f : xr[m0];
    const float b = m1 < 0 ? 0.f : xr[m1];
    w[p] = (unsigned)f2bf(a) | ((unsigned)f2bf(b) << 16);
  }
  xg[g] = w;
}

// ---- P2: W2*g1 -> bf16 A-frag blob [s][i][t][lane] (verified) -------------
__global__ __launch_bounds__(256) void prep_w2g_k(
    const float* __restrict__ W2, const float* __restrict__ g1,
    unsigned short* __restrict__ w2g) {
  const int tid = blockIdx.x * 256 + threadIdx.x;   // 524288
  const int l = tid & 63;
  const int t = (tid >> 6) & 15;
  const int i = (tid >> 10) & 7;
  const int s = tid >> 13;
  const int n = i * 32 + (l & 31);
  const int h = l >> 5;
  const float* w = W2 + (size_t)s * 65536;          // [k][n]
  const float* g = g1 + s * 256;
  u16x8 v;
#pragma unroll
  for (int j = 0; j < 8; ++j) {
    const int k = t * 16 + h * 8 + j;
    v[j] = f2bf(w[k * 256 + n] * g[k]);
  }
  ((u16x8*)w2g)[tid] = v;
}

// ---- P3: u[n], c2[n] packed bf16 (verified) -------------------------------
__global__ __launch_bounds__(256) void prep_uc2_k(
    const float* __restrict__ W2, const float* __restrict__ g1,
    const float* __restrict__ be1, const float* __restrict__ b2,
    unsigned* __restrict__ uc2) {
  const int tid = blockIdx.x * 256 + threadIdx.x;   // 16384
  const int s = tid >> 8, n = tid & 255;
  const float* w = W2 + (size_t)s * 65536 + n;
  const float* g = g1 + s * 256;
  const float* be = be1 + s * 256;
  float u = 0.f, c = 0.f;
#pragma unroll 8
  for (int k = 0; k < 256; ++k) {
    const float wk = w[k * 256];
    u = fmaf(wk, g[k], u);
    c = fmaf(wk, be[k], c);
  }
  c += b2[tid];
  uc2[tid] = (unsigned)f2bf(u) | ((unsigned)f2bf(c) << 16);
}

// ---- P4: layer-1 A-frags (verified) ---------------------------------------
__global__ __launch_bounds__(256) void prep_a1_k(
    const float* __restrict__ W1, const float* __restrict__ b1,
    unsigned short* __restrict__ a1b) {
  const int tid = blockIdx.x * 256 + threadIdx.x;   // 32768
  const int l = tid & 63;
  const int i = (tid >> 6) & 7;
  const int s = tid >> 9;
  const int n = i * 32 + (l & 31);
  const float* w = W1 + (size_t)s * 72 * 256;
  u16x8 v;
#pragma unroll
  for (int j = 0; j < 8; ++j) v[j] = 0;
  if (l < 32) {
#pragma unroll
    for (int j = 0; j < 8; ++j) v[j] = f2bf(w[(64 + j) * 256 + n]);
  } else {
    v[0] = f2bf(w[s * 256 + n] + b1[s * 256 + n]);  // c1, rides k=8 (ones slot)
  }
  ((u16x8*)a1b)[tid] = v;
}

// ---- P5: layer-3 A-frags (verified) ---------------------------------------
__global__ __launch_bounds__(256) void prep_wpg_k(
    const float* __restrict__ Wp, const float* __restrict__ g2,
    const float* __restrict__ be2, const float* __restrict__ bp,
    unsigned short* __restrict__ wpg) {
  const int tid = blockIdx.x * 256 + threadIdx.x;   // 69632
  const int l = tid & 63;
  const int r = tid >> 6;
  const int t = r % 17;
  const int s = r / 17;
  const int a = l & 31;
  const int h = l >> 5;
  u16x8 v;
#pragma unroll
  for (int j = 0; j < 8; ++j) v[j] = 0;
  if (t < 16) {
    if (a < 16) {
      const float* w = Wp + (size_t)s * 4096;       // [k][a]
      const float* g = g2 + s * 256;
#pragma unroll
      for (int j = 0; j < 8; ++j) {
        const int k = t * 16 + h * 8 + j;
        v[j] = f2bf(w[k * 16 + a] * g[k]);
      }
    }
  } else if (h == 0 && a < 16) {
    const float* w = Wp + (size_t)s * 4096;
    float up = 0.f, cp = 0.f;
#pragma unroll 8
    for (int k = 0; k < 256; ++k) {
      const float wk = w[k * 16 + a];
      up = fmaf(wk, g2[s * 256 + k], up);
      cp = fmaf(wk, be2[s * 256 + k], cp);
    }
    cp += bp[s * 16 + a];
    v[0] = f2bf(up); v[1] = f2bf(cp);
  }
  ((u16x8*)wpg)[tid] = v;
}

// ---- pack one 32-n f32x16 tile -> two B-frags (pair-swap, verified) -------
__device__ __forceinline__ void pack_tile(const f32x16& a,
                                          unsigned* f0, unsigned* f1) {
  unsigned w0 = cvtpk(a[0], a[1]),   w1 = cvtpk(a[2], a[3]);
  unsigned w2 = cvtpk(a[4], a[5]),   w3 = cvtpk(a[6], a[7]);
  unsigned w4 = cvtpk(a[8], a[9]),   w5 = cvtpk(a[10], a[11]);
  unsigned w6 = cvtpk(a[12], a[13]), w7 = cvtpk(a[14], a[15]);
  swap2(w0, w2); swap2(w1, w3); swap2(w4, w6); swap2(w5, w7);
  f0[0] = w0; f0[1] = w1; f0[2] = w2; f0[3] = w3;
  f1[0] = w4; f1[1] = w5; f1[2] = w6; f1[3] = w7;
}

// ---- leaky + packed stats on one tile: acc -> yv, s2/q2 accumulate --------
__device__ __forceinline__ void leaky_stats(const f32x16& acc, f32x16& yv,
                                            f32x2& s2, f32x2& q2,
                                            const f32x2 c01) {
  const f32x2* ap = (const f32x2*)&acc;
  f32x2* yp = (f32x2*)&yv;
#pragma unroll
  for (int m = 0; m < 8; ++m) {
    const f32x2 v2 = ap[m];
    const f32x2 m2 = pk_mul(c01, v2);
    f32x2 y;
    y.x = fmaxf(v2.x, m2.x);
    y.y = fmaxf(v2.y, m2.y);
    yp[m] = y;
    s2 = pk_add(s2, y);
    q2 = pk_fma(y, y, q2);
  }
}

// ---- main fused kernel: full-LDS operands + prefab B1 + pipelined L1 ------
__global__ __launch_bounds__(512, 2) void actor_main(
    const u32x4* __restrict__ xg,
    const unsigned short* __restrict__ w2g, const unsigned* __restrict__ uc2,
    const unsigned short* __restrict__ a1b, const unsigned short* __restrict__ wpg,
    float* __restrict__ out) {
  extern __shared__ char lds[];                 // 128KB W2g blob
  const int tid = threadIdx.x;
  const int wv = tid >> 6;
  const int l = tid & 63;
  const int bl = l & 31;
  const int h = l >> 5;
  const int s = blockIdx.x >> 2;                // same-state blocks temporally adjacent
  const int rowstart = (blockIdx.x & 3) << 12;

  { // stage W2g blob (128KB), linear, conflict-free
    const u32x4* src = (const u32x4*)(w2g + (size_t)s * 65536);
    u32x4* dst = (u32x4*)lds;
#pragma unroll
    for (int i = 0; i < 16; ++i) dst[i * 512 + tid] = src[i * 512 + tid];
  }

  unsigned aext[8];
#pragma unroll
  for (int i = 0; i < 8; ++i) {
    const unsigned t = uc2[(s * 8 + i) * 32 + bl];
    aext[i] = h ? 0u : t;
  }
  const bf16x8* A1 = ((const bf16x8*)a1b) + (size_t)(s * 8) * 64 + l;
  const bf16x8* A3 = ((const bf16x8*)wpg) + (size_t)(s * 17) * 64 + l;
  const char* ldsl = lds + (l << 4);
  const u32x4* XG = xg + ((size_t)s << 14);

  const int rbase = rowstart + wv * 32 + bl;
  const f32x2 c01 = {0.01f, 0.01f};

  // prologue: prefab B1 words for iter 0 (one coalesced 16B nt load)
  u32x4 gcur = __builtin_nontemporal_load(&XG[rbase]);

  __syncthreads();   // only barrier: W2g staged

  for (int it = 0; it < 16; ++it) {
    const int row = rbase + it * 256;

    // ---- layer-1 B-frag directly from prefab words ----------------------
    U8 B1;
    B1.u[0] = h ? 0x00003F80u : gcur[0];   // h=1: k=8 -> 1.0 (c1 slot)
    B1.u[1] = h ? 0u : gcur[1];
    B1.u[2] = h ? 0u : gcur[2];
    B1.u[3] = h ? 0u : gcur[3];

    // prefetch next iteration's prefab (full iter of latency cover)
    gcur = __builtin_nontemporal_load(&XG[rbase + ((it + 1) & 15) * 256]);

    // ---- phase A: fused L1 -> leaky/stats/pack -> L2, interleaved ------
    f32x2 s2 = {0.f, 0.f}, q2 = {0.f, 0.f};
    f32x16 acc2[8];
    bf16x8 a1n = A1[64];             // A1 frag for tile 1
    bf16x8 Afc[8];
#pragma unroll
    for (int j = 0; j < 8; ++j)      // ds prefetch for t=0
      Afc[j] = *(const bf16x8*)(ldsl + ((j * 16 + 0) << 10));

    f32x16 accP;
    { f32x16 z = {}; accP = MFMA32(A1[0], B1.v, z); }   // tile 0 L1

#pragma unroll
    for (int i = 0; i < 8; ++i) {
      // leaky + packed stats + pack of tile i (VALU; overlaps ds/MAI)
      f32x16 yv;
      leaky_stats(accP, yv, s2, q2, c01);
      U8 Bf0, Bf1;
      pack_tile(yv, Bf0.u, Bf1.u);

      // issue next tile's L1 MFMA now (accP dead; ~17 MFMAs before use)
      if (i < 7) {
        f32x16 z = {};
        accP = MFMA32(a1n, B1.v, z);
        if (i < 6) a1n = A1[(i + 2) * 64];
      }

      // odd-k ds_reads issued early (even-MFMA block covers their latency)
      bf16x8 Afn[8];
#pragma unroll
      for (int j = 0; j < 8; ++j)
        Afn[j] = *(const bf16x8*)(ldsl + ((j * 16 + 2 * i + 1) << 10));

      __builtin_amdgcn_s_setprio(1);
      // k-step t=2i with prefetched Af
#pragma unroll
      for (int j = 0; j < 8; ++j) {
        if (i == 0) { f32x16 zz = {}; acc2[j] = MFMA32(Afc[j], Bf0.v, zz); }
        else        { acc2[j] = MFMA32(Afc[j], Bf0.v, acc2[j]); }
      }
      // k-step t=2i+1
#pragma unroll
      for (int j = 0; j < 8; ++j) acc2[j] = MFMA32(Afn[j], Bf1.v, acc2[j]);
      __builtin_amdgcn_s_setprio(0);

      // prefetch t=2i+2 for next step
      if (i < 7) {
#pragma unroll
        for (int j = 0; j < 8; ++j)
          Afc[j] = *(const bf16x8*)(ldsl + ((j * 16 + 2 * i + 2) << 10));
      }
    }

    // ---- LN1 stats finalize + rank-1 correction k-step ------------------
    float sum = s2.x + s2.y, ssq = q2.x + q2.y;
    sum += __shfl_xor(sum, 32, 64);
    ssq += __shfl_xor(ssq, 32, 64);
    const float m1 = sum * 0.00390625f;
    const float var1 = fmaf(ssq, 0.00390625f, -m1 * m1) + LNEPS;
    const float rho1 = rsqrtf(var1);
    const float std1 = var1 * rho1;               // = 1/rho1
    const unsigned be2w = cvtpk(-m1, std1);
    // prefetch first layer-3 A-frags (VMEM, hidden under corr MFMAs)
    bf16x8 p0 = A3[0], p1 = A3[64];
    {
      U8 Bx; Bx.u[0] = h ? 0u : be2w; Bx.u[1] = 0; Bx.u[2] = 0; Bx.u[3] = 0;
#pragma unroll
      for (int i = 0; i < 8; ++i) {
        U8 Ax; Ax.u[0] = aext[i]; Ax.u[1] = 0; Ax.u[2] = 0; Ax.u[3] = 0;
        acc2[i] = MFMA32(Ax.v, Bx.v, acc2[i]);
      }
    }

    // ---- phase B: fused leaky/stats2/pack + layer-3 (A3 prefetch) -------
    f32x16 a3a = {}, a3b = {};
    s2.x = 0.f; s2.y = 0.f; q2.x = 0.f; q2.y = 0.f;
#pragma unroll
    for (int i = 0; i < 8; ++i) {
      bf16x8 n0, n1;
      if (i < 7) { n0 = A3[(2 * i + 2) * 64]; n1 = A3[(2 * i + 3) * 64]; }
      else       { n0 = A3[16 * 64]; n1 = p1; }
      f32x16 yv;
      leaky_stats(acc2[i], yv, s2, q2, c01);
      U8 Bf0, Bf1;
      pack_tile(yv, Bf0.u, Bf1.u);
      a3a = MFMA32(p0, Bf0.v, a3a);
      a3b = MFMA32(p1, Bf1.v, a3b);
      p0 = n0; p1 = n1;
    }
    float sum2 = s2.x + s2.y, ssq2 = q2.x + q2.y;
    sum2 += __shfl_xor(sum2, 32, 64);
    ssq2 += __shfl_xor(ssq2, 32, 64);
    const float mp = sum2 * 0.00390625f;
    const float qp = ssq2 * 0.00390625f;
    const float var2 = rho1 * rho1 * fmaf(-mp, mp, qp) + LNEPS;
    const float rho2 = rsqrtf(var2);
    const float sigma = rho1 * rho2;
    const float inv = var2 * rho2 * std1;         // = 1/sigma
    const unsigned be3w = cvtpk(-mp, inv);
    { // LN2 rank-1 correction k-step (p0 holds A3[16*64])
      U8 Bx; Bx.u[0] = h ? 0u : be3w; Bx.u[1] = 0; Bx.u[2] = 0; Bx.u[3] = 0;
      a3a = MFMA32(p0, Bx.v, a3a);
    }

    // ---- log-softmax + nt store -----------------------------------------
    float lg[8];
#pragma unroll
    for (int r = 0; r < 8; ++r) lg[r] = sigma * (a3a[r] + a3b[r]);
    float mx = fmaxf(fmaxf(fmaxf(lg[0], lg[1]), fmaxf(lg[2], lg[3])),
                     fmaxf(fmaxf(lg[4], lg[5]), fmaxf(lg[6], lg[7])));
    mx = fmaxf(mx, __shfl_xor(mx, 32, 64));
    float es = 0.f;
#pragma unroll
    for (int r = 0; r < 8; ++r) es += __expf(lg[r] - mx);
    es += __shfl_xor(es, 32, 64);
    const float lse = mx + __logf(es);

    const size_t ob = (((size_t)row << 6) + s) * 16 + (h << 2);
    f32x4 v0 = {lg[0], lg[1], lg[2], lg[3]};
    f32x4 v1 = {lg[4], lg[5], lg[6], lg[7]};
    __builtin_nontemporal_store(v0, (f32x4*)(out + ob));
    __builtin_nontemporal_store(v1, (f32x4*)(out + ob + 8));
    f32x4 w0 = {lg[0] - lse, lg[1] - lse, lg[2] - lse, lg[3] - lse};
    f32x4 w1 = {lg[4] - lse, lg[5] - lse, lg[6] - lse, lg[7] - lse};
    __builtin_nontemporal_store(w0, (f32x4*)(out + 16777216 + ob));
    __builtin_nontemporal_store(w1, (f32x4*)(out + 16777216 + ob + 8));
  }
}

extern "C" void kernel_launch(void* const* d_in, const int* in_sizes, int n_in,
                              void* d_out, int out_size, void* d_ws, size_t ws_size,
                              hipStream_t stream) {
  const float* x    = (const float*)d_in[0];
  const int*   oidx = (const int*)d_in[1];
  const unsigned* omask = (const unsigned*)d_in[2];
  const float* W1 = (const float*)d_in[3];
  const float* b1 = (const float*)d_in[4];
  const float* g1 = (const float*)d_in[5];
  const float* be1 = (const float*)d_in[6];
  const float* W2 = (const float*)d_in[7];
  const float* b2 = (const float*)d_in[8];
  const float* g2 = (const float*)d_in[9];
  const float* be2 = (const float*)d_in[10];
  const float* Wp = (const float*)d_in[11];
  const float* bp = (const float*)d_in[12];
  float* out = (float*)d_out;

  char* ws = (char*)d_ws;
  unsigned short* wsW2G = (unsigned short*)(ws + WS_W2G);
  unsigned short* wsA1  = (unsigned short*)(ws + WS_A1);
  unsigned short* wsWPG = (unsigned short*)(ws + WS_WPG);
  unsigned*       wsUC2 = (unsigned*)(ws + WS_UC2);
  int*            wsMIDX = (int*)(ws + WS_MIDX);
  u32x4*          wsXG   = (u32x4*)(ws + WS_XG);

  prep_midx_k<<<1, 512, 0, stream>>>(oidx, omask, wsMIDX);
  prep_xg_k<<<4096, 256, 0, stream>>>(x, wsMIDX, wsXG);
  prep_w2g_k<<<2048, 256, 0, stream>>>(W2, g1, wsW2G);
  prep_uc2_k<<<64, 256, 0, stream>>>(W2, g1, be1, b2, wsUC2);
  prep_a1_k<<<128, 256, 0, stream>>>(W1, b1, wsA1);
  prep_wpg_k<<<272, 256, 0, stream>>>(Wp, g2, be2, bp, wsWPG);

  hipFuncSetAttribute((const void*)actor_main,
                      hipFuncAttributeMaxDynamicSharedMemorySize, 131072);
  actor_main<<<256, 512, 131072, stream>>>(
      wsXG, wsW2G, wsUC2, wsA1, wsWPG, out);
}

// Round 10
// 280.607 us; speedup vs baseline: 1.5399x; 1.1155x over previous
//
#include <hip/hip_runtime.h>

#define LNEPS 1e-5f

typedef __attribute__((ext_vector_type(8)))  short          bf16x8;
typedef __attribute__((ext_vector_type(8)))  unsigned short u16x8;
typedef __attribute__((ext_vector_type(4)))  float          f32x4;
typedef __attribute__((ext_vector_type(16))) float          f32x16;
typedef __attribute__((ext_vector_type(4)))  unsigned int   u32x4;

#define MFMA32(a, b, c) __builtin_amdgcn_mfma_f32_32x32x16_bf16((a), (b), (c), 0, 0, 0)

// workspace byte offsets (~10.1 MB)
#define WS_W2G  0          // 64 * 128KB  : W2*g1 ^T blob [s][i][t][lane] bf16x8
#define WS_A1   8388608    // 64*8*64*16B : layer-1 A-frags (W1o^T | c1)
#define WS_WPG  8912896    // 64*17*64*16B: layer-3 A-frags (Wp*g2 ^T | up,cp)
#define WS_UC2  10027008   // 64*256*4B   : packed bf16 (u[n], c2[n])
#define WS_MIDX 10092544   // 512*4B      : masked neighbor idx (-1 = masked)

union U8 { bf16x8 v; unsigned u[4]; };

__device__ __forceinline__ unsigned short f2bf(float v) {
  union { float f; unsigned u; } a; a.f = v;
  unsigned r = a.u + 0x7fffu + ((a.u >> 16) & 1u);   // RTNE
  return (unsigned short)(r >> 16);
}
__device__ __forceinline__ unsigned cvtpk(float lo, float hi) {
  unsigned r;
  asm("v_cvt_pk_bf16_f32 %0, %1, %2" : "=v"(r) : "v"(lo), "v"(hi));
  return r;
}
// swaps: a -> [a_lo | b_lo], b -> [a_hi | b_hi]
__device__ __forceinline__ void swap2(unsigned& a, unsigned& b) {
  asm volatile("v_permlane32_swap_b32 %0, %1" : "+v"(a), "+v"(b));
}
// broadcast form: lo = [w_lo|w_lo], hi = [w_hi|w_hi]
__device__ __forceinline__ void plswap(unsigned w, unsigned& lo, unsigned& hi) {
  unsigned a = w, b = w;
  asm volatile("v_permlane32_swap_b32 %0, %1" : "+v"(a), "+v"(b));
  lo = a; hi = b;
}

// ---- P1: mask format detect + masked index table (verified) ---------------
__global__ void prep_midx_k(const int* __restrict__ oidx,
                            const unsigned* __restrict__ mask32,
                            int* __restrict__ midx) {
  __shared__ int fgt1, ffl;
  const int t = threadIdx.x;            // 512 threads
  if (t == 0) { fgt1 = 0; ffl = 0; }
  __syncthreads();
  if (t < 128) {
    unsigned wv = mask32[t];
    if (wv == 0x3f800000u) atomicOr(&ffl, 1);
    else if (wv > 1u)      atomicOr(&fgt1, 1);
  }
  __syncthreads();
  const int mode = ffl ? 2 : (fgt1 ? 1 : 0);
  int mv;
  if (mode == 2)      mv = (((const float*)mask32)[t] != 0.0f) ? 1 : 0;
  else if (mode == 1) mv = (int)((const unsigned char*)mask32)[t];
  else                mv = ((const int*)mask32)[t];
  midx[t] = (mv != 0) ? oidx[t] : -1;
}

// ---- P2: W2*g1 -> bf16 A-frag blob [s][i][t][lane] (verified) -------------
__global__ __launch_bounds__(256) void prep_w2g_k(
    const float* __restrict__ W2, const float* __restrict__ g1,
    unsigned short* __restrict__ w2g) {
  const int tid = blockIdx.x * 256 + threadIdx.x;   // 524288
  const int l = tid & 63;
  const int t = (tid >> 6) & 15;
  const int i = (tid >> 10) & 7;
  const int s = tid >> 13;
  const int n = i * 32 + (l & 31);
  const int h = l >> 5;
  const float* w = W2 + (size_t)s * 65536;          // [k][n]
  const float* g = g1 + s * 256;
  u16x8 v;
#pragma unroll
  for (int j = 0; j < 8; ++j) {
    const int k = t * 16 + h * 8 + j;
    v[j] = f2bf(w[k * 256 + n] * g[k]);
  }
  ((u16x8*)w2g)[tid] = v;
}

// ---- P3: u[n], c2[n] packed bf16 (verified) -------------------------------
__global__ __launch_bounds__(256) void prep_uc2_k(
    const float* __restrict__ W2, const float* __restrict__ g1,
    const float* __restrict__ be1, const float* __restrict__ b2,
    unsigned* __restrict__ uc2) {
  const int tid = blockIdx.x * 256 + threadIdx.x;   // 16384
  const int s = tid >> 8, n = tid & 255;
  const float* w = W2 + (size_t)s * 65536 + n;
  const float* g = g1 + s * 256;
  const float* be = be1 + s * 256;
  float u = 0.f, c = 0.f;
#pragma unroll 8
  for (int k = 0; k < 256; ++k) {
    const float wk = w[k * 256];
    u = fmaf(wk, g[k], u);
    c = fmaf(wk, be[k], c);
  }
  c += b2[tid];
  uc2[tid] = (unsigned)f2bf(u) | ((unsigned)f2bf(c) << 16);
}

// ---- P4: layer-1 A-frags (verified) ---------------------------------------
__global__ __launch_bounds__(256) void prep_a1_k(
    const float* __restrict__ W1, const float* __restrict__ b1,
    unsigned short* __restrict__ a1b) {
  const int tid = blockIdx.x * 256 + threadIdx.x;   // 32768
  const int l = tid & 63;
  const int i = (tid >> 6) & 7;
  const int s = tid >> 9;
  const int n = i * 32 + (l & 31);
  const float* w = W1 + (size_t)s * 72 * 256;
  u16x8 v;
#pragma unroll
  for (int j = 0; j < 8; ++j) v[j] = 0;
  if (l < 32) {
#pragma unroll
    for (int j = 0; j < 8; ++j) v[j] = f2bf(w[(64 + j) * 256 + n]);
  } else {
    v[0] = f2bf(w[s * 256 + n] + b1[s * 256 + n]);  // c1, rides k=8 (ones slot)
  }
  ((u16x8*)a1b)[tid] = v;
}

// ---- P5: layer-3 A-frags (verified) ---------------------------------------
__global__ __launch_bounds__(256) void prep_wpg_k(
    const float* __restrict__ Wp, const float* __restrict__ g2,
    const float* __restrict__ be2, const float* __restrict__ bp,
    unsigned short* __restrict__ wpg) {
  const int tid = blockIdx.x * 256 + threadIdx.x;   // 69632
  const int l = tid & 63;
  const int r = tid >> 6;
  const int t = r % 17;
  const int s = r / 17;
  const int a = l & 31;
  const int h = l >> 5;
  u16x8 v;
#pragma unroll
  for (int j = 0; j < 8; ++j) v[j] = 0;
  if (t < 16) {
    if (a < 16) {
      const float* w = Wp + (size_t)s * 4096;       // [k][a]
      const float* g = g2 + s * 256;
#pragma unroll
      for (int j = 0; j < 8; ++j) {
        const int k = t * 16 + h * 8 + j;
        v[j] = f2bf(w[k * 16 + a] * g[k]);
      }
    }
  } else if (h == 0 && a < 16) {
    const float* w = Wp + (size_t)s * 4096;
    float up = 0.f, cp = 0.f;
#pragma unroll 8
    for (int k = 0; k < 256; ++k) {
      const float wk = w[k * 16 + a];
      up = fmaf(wk, g2[s * 256 + k], up);
      cp = fmaf(wk, be2[s * 256 + k], cp);
    }
    cp += bp[s * 16 + a];
    v[0] = f2bf(up); v[1] = f2bf(cp);
  }
  ((u16x8*)wpg)[tid] = v;
}

// ---- pack one 32-n f32x16 tile -> two B-frags (pair-swap, verified) -------
__device__ __forceinline__ void pack_tile(const f32x16& a,
                                          unsigned* f0, unsigned* f1) {
  unsigned w0 = cvtpk(a[0], a[1]),   w1 = cvtpk(a[2], a[3]);
  unsigned w2 = cvtpk(a[4], a[5]),   w3 = cvtpk(a[6], a[7]);
  unsigned w4 = cvtpk(a[8], a[9]),   w5 = cvtpk(a[10], a[11]);
  unsigned w6 = cvtpk(a[12], a[13]), w7 = cvtpk(a[14], a[15]);
  swap2(w0, w2); swap2(w1, w3); swap2(w4, w6); swap2(w5, w7);
  f0[0] = w0; f0[1] = w1; f0[2] = w2; f0[3] = w3;
  f1[0] = w4; f1[1] = w5; f1[2] = w6; f1[3] = w7;
}

// ---- main fused kernel: R4 champion + one-ahead L1 + shared zero C --------
__global__ __launch_bounds__(512, 2) void actor_main(
    const float* __restrict__ x, const int* __restrict__ midx,
    const unsigned short* __restrict__ w2g, const unsigned* __restrict__ uc2,
    const unsigned short* __restrict__ a1b, const unsigned short* __restrict__ wpg,
    float* __restrict__ out) {
  extern __shared__ char lds[];                 // 128KB W2g blob
  const int tid = threadIdx.x;
  const int wv = tid >> 6;
  const int l = tid & 63;
  const int bl = l & 31;
  const int h = l >> 5;
  const int s = blockIdx.x >> 2;                // same-state blocks temporally adjacent
  const int rowstart = (blockIdx.x & 3) << 12;

  { // stage W2g blob (128KB), linear, conflict-free
    const u32x4* src = (const u32x4*)(w2g + (size_t)s * 65536);
    u32x4* dst = (u32x4*)lds;
#pragma unroll
    for (int i = 0; i < 16; ++i) dst[i * 512 + tid] = src[i * 512 + tid];
  }

  unsigned aext[8];
#pragma unroll
  for (int i = 0; i < 8; ++i) {
    const unsigned t = uc2[(s * 8 + i) * 32 + bl];
    aext[i] = h ? 0u : t;
  }
  const int4 mi4 = ((const int4*)(midx + s * 8))[h];
  const bf16x8* A1 = ((const bf16x8*)a1b) + (size_t)(s * 8) * 64 + l;
  const bf16x8* A3 = ((const bf16x8*)wpg) + (size_t)(s * 17) * 64 + l;
  const char* ldsl = lds + (l << 4);

  const float* xbase = x + (size_t)(rowstart + wv * 32 + bl) * 64;

  // prologue gather (iter 0)
  float ga = mi4.x < 0 ? 0.f : xbase[mi4.x];
  float gb = mi4.y < 0 ? 0.f : xbase[mi4.y];
  float gc = mi4.z < 0 ? 0.f : xbase[mi4.z];
  float gd = mi4.w < 0 ? 0.f : xbase[mi4.w];

  __syncthreads();   // only barrier: W2g staged

  for (int it = 0; it < 16; ++it) {
    const int row = rowstart + it * 256 + wv * 32 + bl;
    f32x16 Z = {};   // shared zero C-operand for all zero-start MFMAs

    // ---- build layer-1 B-frag from current gather ----------------------
    unsigned oa0, ob0, oa1, ob1;
    plswap(cvtpk(ga, gb), oa0, ob0);
    plswap(cvtpk(gc, gd), oa1, ob1);
    U8 B1;
    B1.u[0] = h ? 0x00003F80u : oa0;   // h=1: k=8 -> 1.0 (c1 slot)
    B1.u[1] = h ? 0u : oa1;
    B1.u[2] = h ? 0u : ob0;
    B1.u[3] = h ? 0u : ob1;

    // ---- prefetch next iteration's gather (full iter of latency cover) --
    {
      const float* xn = xbase + (size_t)(((it + 1) & 15) * 256) * 64;
      ga = mi4.x < 0 ? 0.f : xn[mi4.x];
      gb = mi4.y < 0 ? 0.f : xn[mi4.y];
      gc = mi4.z < 0 ? 0.f : xn[mi4.z];
      gd = mi4.w < 0 ? 0.f : xn[mi4.w];
    }

    // ---- phase A: fused L1 -> leaky/stats/pack -> L2, interleaved ------
    float s0 = 0.f, s1 = 0.f, q0 = 0.f, q1 = 0.f;
    f32x16 acc2[8];
    bf16x8 a1n = A1[64];             // A1 frag for tile 1
    bf16x8 Afc[8];
#pragma unroll
    for (int j = 0; j < 8; ++j)      // ds prefetch for t=0
      Afc[j] = *(const bf16x8*)(ldsl + ((j * 16 + 0) << 10));

    f32x16 accP = MFMA32(A1[0], B1.v, Z);   // tile 0 L1

#pragma unroll
    for (int i = 0; i < 8; ++i) {
      // leaky + stats + pack of tile i (VALU; overlaps in-flight ds/MAI)
      f32x16 yv;
#pragma unroll
      for (int r = 0; r < 16; ++r) {
        float v = accP[r];
        v = fmaxf(v, 0.01f * v);
        yv[r] = v;
        if (r & 1) { s1 += v; q1 = fmaf(v, v, q1); }
        else       { s0 += v; q0 = fmaf(v, v, q0); }
      }
      U8 Bf0, Bf1;
      pack_tile(yv, Bf0.u, Bf1.u);

      // issue next tile's L1 MFMA now (accP dead; ~17 MFMAs before use)
      if (i < 7) {
        accP = MFMA32(a1n, B1.v, Z);
        if (i < 6) a1n = A1[(i + 2) * 64];
      }

      // k-step t=2i with prefetched Af
#pragma unroll
      for (int j = 0; j < 8; ++j) {
        if (i == 0) acc2[j] = MFMA32(Afc[j], Bf0.v, Z);
        else        acc2[j] = MFMA32(Afc[j], Bf0.v, acc2[j]);
      }
      // load + k-step t=2i+1 (even MFMAs hide part of the ds latency)
      bf16x8 Afn[8];
#pragma unroll
      for (int j = 0; j < 8; ++j)
        Afn[j] = *(const bf16x8*)(ldsl + ((j * 16 + 2 * i + 1) << 10));
#pragma unroll
      for (int j = 0; j < 8; ++j) acc2[j] = MFMA32(Afn[j], Bf1.v, acc2[j]);
      // prefetch t=2i+2 for next step
      if (i < 7) {
#pragma unroll
        for (int j = 0; j < 8; ++j)
          Afc[j] = *(const bf16x8*)(ldsl + ((j * 16 + 2 * i + 2) << 10));
      }
    }

    // ---- LN1 stats finalize + rank-1 correction k-step ------------------
    float sum = s0 + s1, ssq = q0 + q1;
    sum += __shfl_xor(sum, 32, 64);
    ssq += __shfl_xor(ssq, 32, 64);
    const float m1 = sum * 0.00390625f;
    const float var1 = fmaf(ssq, 0.00390625f, -m1 * m1) + LNEPS;
    const float rho1 = rsqrtf(var1);
    const float std1 = var1 * rho1;               // = 1/rho1
    const unsigned be2w = cvtpk(-m1, std1);
    // prefetch first layer-3 A-frags (VMEM, hidden under corr MFMAs)
    bf16x8 p0 = A3[0], p1 = A3[64];
    {
      U8 Bx; Bx.u[0] = h ? 0u : be2w; Bx.u[1] = 0; Bx.u[2] = 0; Bx.u[3] = 0;
#pragma unroll
      for (int i = 0; i < 8; ++i) {
        U8 Ax; Ax.u[0] = aext[i]; Ax.u[1] = 0; Ax.u[2] = 0; Ax.u[3] = 0;
        acc2[i] = MFMA32(Ax.v, Bx.v, acc2[i]);
      }
    }

    // ---- phase B: fused leaky/stats2/pack + layer-3 (A3 prefetch) -------
    f32x16 a3a, a3b;
    s0 = s1 = q0 = q1 = 0.f;
#pragma unroll
    for (int i = 0; i < 8; ++i) {
      bf16x8 n0, n1;
      if (i < 7) { n0 = A3[(2 * i + 2) * 64]; n1 = A3[(2 * i + 3) * 64]; }
      else       { n0 = A3[16 * 64]; n1 = p1; }
      f32x16 yv;
#pragma unroll
      for (int r = 0; r < 16; ++r) {
        float v = acc2[i][r];
        v = fmaxf(v, 0.01f * v);
        yv[r] = v;
        if (r & 1) { s1 += v; q1 = fmaf(v, v, q1); }
        else       { s0 += v; q0 = fmaf(v, v, q0); }
      }
      U8 Bf0, Bf1;
      pack_tile(yv, Bf0.u, Bf1.u);
      if (i == 0) {
        a3a = MFMA32(p0, Bf0.v, Z);
        a3b = MFMA32(p1, Bf1.v, Z);
      } else {
        a3a = MFMA32(p0, Bf0.v, a3a);
        a3b = MFMA32(p1, Bf1.v, a3b);
      }
      p0 = n0; p1 = n1;
    }
    float sum2 = s0 + s1, ssq2 = q0 + q1;
    sum2 += __shfl_xor(sum2, 32, 64);
    ssq2 += __shfl_xor(ssq2, 32, 64);
    const float mp = sum2 * 0.00390625f;
    const float qp = ssq2 * 0.00390625f;
    const float var2 = rho1 * rho1 * fmaf(-mp, mp, qp) + LNEPS;
    const float rho2 = rsqrtf(var2);
    const float sigma = rho1 * rho2;
    const float inv = var2 * rho2 * std1;         // = 1/sigma
    const unsigned be3w = cvtpk(-mp, inv);
    { // LN2 rank-1 correction k-step (p0 holds A3[16*64])
      U8 Bx; Bx.u[0] = h ? 0u : be3w; Bx.u[1] = 0; Bx.u[2] = 0; Bx.u[3] = 0;
      a3a = MFMA32(p0, Bx.v, a3a);
    }

    // ---- log-softmax + store --------------------------------------------
    float lg[8];
#pragma unroll
    for (int r = 0; r < 8; ++r) lg[r] = sigma * (a3a[r] + a3b[r]);
    float mx = fmaxf(fmaxf(fmaxf(lg[0], lg[1]), fmaxf(lg[2], lg[3])),
                     fmaxf(fmaxf(lg[4], lg[5]), fmaxf(lg[6], lg[7])));
    mx = fmaxf(mx, __shfl_xor(mx, 32, 64));
    float es = 0.f;
#pragma unroll
    for (int r = 0; r < 8; ++r) es += __expf(lg[r] - mx);
    es += __shfl_xor(es, 32, 64);
    const float lse = mx + __logf(es);

    const size_t ob = (((size_t)row << 6) + s) * 16 + (h << 2);
    f32x4 v0 = {lg[0], lg[1], lg[2], lg[3]};
    f32x4 v1 = {lg[4], lg[5], lg[6], lg[7]};
    *(f32x4*)(out + ob) = v0;
    *(f32x4*)(out + ob + 8) = v1;
    f32x4 w0 = {lg[0] - lse, lg[1] - lse, lg[2] - lse, lg[3] - lse};
    f32x4 w1 = {lg[4] - lse, lg[5] - lse, lg[6] - lse, lg[7] - lse};
    *(f32x4*)(out + 16777216 + ob) = w0;
    *(f32x4*)(out + 16777216 + ob + 8) = w1;
  }
}

extern "C" void kernel_launch(void* const* d_in, const int* in_sizes, int n_in,
                              void* d_out, int out_size, void* d_ws, size_t ws_size,
                              hipStream_t stream) {
  const float* x    = (const float*)d_in[0];
  const int*   oidx = (const int*)d_in[1];
  const unsigned* omask = (const unsigned*)d_in[2];
  const float* W1 = (const float*)d_in[3];
  const float* b1 = (const float*)d_in[4];
  const float* g1 = (const float*)d_in[5];
  const float* be1 = (const float*)d_in[6];
  const float* W2 = (const float*)d_in[7];
  const float* b2 = (const float*)d_in[8];
  const float* g2 = (const float*)d_in[9];
  const float* be2 = (const float*)d_in[10];
  const float* Wp = (const float*)d_in[11];
  const float* bp = (const float*)d_in[12];
  float* out = (float*)d_out;

  char* ws = (char*)d_ws;
  unsigned short* wsW2G = (unsigned short*)(ws + WS_W2G);
  unsigned short* wsA1  = (unsigned short*)(ws + WS_A1);
  unsigned short* wsWPG = (unsigned short*)(ws + WS_WPG);
  unsigned*       wsUC2 = (unsigned*)(ws + WS_UC2);
  int*            wsMIDX = (int*)(ws + WS_MIDX);

  prep_midx_k<<<1, 512, 0, stream>>>(oidx, omask, wsMIDX);
  prep_w2g_k<<<2048, 256, 0, stream>>>(W2, g1, wsW2G);
  prep_uc2_k<<<64, 256, 0, stream>>>(W2, g1, be1, b2, wsUC2);
  prep_a1_k<<<128, 256, 0, stream>>>(W1, b1, wsA1);
  prep_wpg_k<<<272, 256, 0, stream>>>(Wp, g2, be2, bp, wsWPG);

  hipFuncSetAttribute((const void*)actor_main,
                      hipFuncAttributeMaxDynamicSharedMemorySize, 131072);
  actor_main<<<256, 512, 131072, stream>>>(
      x, wsMIDX, wsW2G, wsUC2, wsA1, wsWPG, out);
}